// Round 1
// baseline (124.693 us; speedup 1.0000x reference)
//
#include <hip/hip_runtime.h>

#define NHEADS 8
#define DHEAD 64
#define CIN 256
#define SLEN 1024
#define VDIM 256
#define PT_STRIDE 1048   // elems; 2096B = 524 words, 524%32=12 -> 2-way (free) banks

typedef __attribute__((ext_vector_type(8))) short bf16x8;
typedef __attribute__((ext_vector_type(4))) float f32x4;

__device__ __forceinline__ unsigned short f2bf(float x) {
    unsigned int u = __builtin_bit_cast(unsigned int, x);
    u += 0x7fffu + ((u >> 16) & 1u);   // round-to-nearest-even
    return (unsigned short)(u >> 16);
}

extern "C" __global__ void __launch_bounds__(1024)
attn_fused_kernel(const float* __restrict__ queries,
                  const float* __restrict__ keys,
                  const float* __restrict__ values,
                  const float* __restrict__ Wq,
                  const float* __restrict__ bq,
                  const float* __restrict__ Wk,
                  const float* __restrict__ bk,
                  float* __restrict__ out)
{
    __shared__ __align__(16) float          q_lds[CIN];            // 1 KB
    __shared__ float                        qh[NHEADS * DHEAD];    // 2 KB
    __shared__ __align__(16) unsigned short rb[CIN * 16];          // 8 KB  r as bf16, [i][hcol(16)]
    __shared__ __align__(16) float          sc[SLEN * NHEADS];     // 32 KB scores [s][h]
    __shared__ __align__(16) unsigned short pT[16 * PT_STRIDE];    // 33.5 KB p bf16, [hrow(16)][s]
    __shared__ float                        red[16 * NHEADS];      // wave partials
    __shared__ float                        gmax[NHEADS];
    __shared__ float                        gsum[NHEADS];
    __shared__ float                        c_lds[NHEADS];

    const int b    = blockIdx.x;
    const int t    = threadIdx.x;
    const int lane = t & 63;
    const int wave = t >> 6;
    const int col  = lane & 15;   // MFMA: A-row / B-col / C-col
    const int kgrp = lane >> 4;   // MFMA: k-octet group

    // ---------------- phase 0a: queries[b] -> LDS ----------------
    if (t < CIN / 4) {
        ((float4*)q_lds)[t] = ((const float4*)(queries + (size_t)b * CIN))[t];
    }
    __syncthreads();

    // ---------------- phase 0b: qh[h*64+d] = Wq[h,d,:]@q + bq ----------------
    if (t < NHEADS * DHEAD) {
        const float4* wq = (const float4*)(Wq + (size_t)t * CIN);
        const float4* q4 = (const float4*)q_lds;
        float acc = bq[t];
        #pragma unroll 8
        for (int i = 0; i < CIN / 4; ++i) {
            float4 w = wq[i], q = q4[i];
            acc += w.x * q.x + w.y * q.y + w.z * q.z + w.w * q.w;
        }
        qh[t] = acc;
    }
    __syncthreads();

    // ---------------- phase 0c: r[h][i] = sum_d qh[h][d]*Wk[h,d,i]; c[h] ----------------
    for (int idx = t; idx < NHEADS * CIN; idx += 1024) {
        int h = idx >> 8;
        int i = idx & 255;
        const float* wk = Wk + ((size_t)h * DHEAD) * CIN + i;
        float acc = 0.f;
        #pragma unroll 8
        for (int d = 0; d < DHEAD; ++d) acc += qh[h * DHEAD + d] * wk[(size_t)d * CIN];
        rb[i * 16 + h]     = f2bf(acc);
        rb[i * 16 + 8 + h] = 0;   // zero pad cols 8..15
    }
    if (t < NHEADS) {
        float acc = 0.f;
        for (int d = 0; d < DHEAD; ++d) acc += qh[t * DHEAD + d] * bk[t * DHEAD + d];
        c_lds[t] = acc;
    }
    __syncthreads();

    // ---------------- phase 1: scores[s][h] = (keys@r + c)*scale via MFMA ----------------
    // B-frags (same for all tiles of this wave): B[k][col] = rb[k][col]
    bf16x8 bfr[8];
    #pragma unroll
    for (int kk = 0; kk < 8; ++kk) {
        unsigned short* bp = (unsigned short*)&bfr[kk];
        #pragma unroll
        for (int j = 0; j < 8; ++j)
            bp[j] = rb[(kk * 32 + kgrp * 8 + j) * 16 + col];
    }
    const float* kbase = keys + (size_t)b * SLEN * CIN;
    for (int tile = wave; tile < SLEN / 16; tile += 16) {
        int s0 = tile * 16;
        f32x4 acc = {0.f, 0.f, 0.f, 0.f};
        const float* arow = kbase + (size_t)(s0 + col) * CIN + kgrp * 8;
        #pragma unroll
        for (int kk = 0; kk < 8; ++kk) {
            float4 a0 = *(const float4*)(arow + kk * 32);
            float4 a1 = *(const float4*)(arow + kk * 32 + 4);
            bf16x8 af;
            unsigned short* ap = (unsigned short*)&af;
            ap[0] = f2bf(a0.x); ap[1] = f2bf(a0.y); ap[2] = f2bf(a0.z); ap[3] = f2bf(a0.w);
            ap[4] = f2bf(a1.x); ap[5] = f2bf(a1.y); ap[6] = f2bf(a1.z); ap[7] = f2bf(a1.w);
            acc = __builtin_amdgcn_mfma_f32_16x16x32_bf16(af, bfr[kk], acc, 0, 0, 0);
        }
        if (col < NHEADS) {
            float c = c_lds[col];
            #pragma unroll
            for (int m = 0; m < 4; ++m)
                sc[(s0 + kgrp * 4 + m) * NHEADS + col] = (acc[m] + c) * 0.125f;
        }
    }
    __syncthreads();

    // ---------------- phase 2: softmax over s (thread t owns s = t) ----------------
    float v[8];
    {
        float4 x0 = *(const float4*)&sc[t * NHEADS + 0];
        float4 x1 = *(const float4*)&sc[t * NHEADS + 4];
        v[0] = x0.x; v[1] = x0.y; v[2] = x0.z; v[3] = x0.w;
        v[4] = x1.x; v[5] = x1.y; v[6] = x1.z; v[7] = x1.w;
    }
    float m8[8];
    #pragma unroll
    for (int h = 0; h < NHEADS; ++h) {
        float x = v[h];
        #pragma unroll
        for (int mask = 1; mask < 64; mask <<= 1)
            x = fmaxf(x, __shfl_xor(x, mask, 64));
        m8[h] = x;
    }
    if (lane == 0) {
        #pragma unroll
        for (int h = 0; h < NHEADS; ++h) red[wave * NHEADS + h] = m8[h];
    }
    __syncthreads();
    if (wave == 0) {
        int w = lane >> 3, h = lane & 7;
        float x = fmaxf(red[w * NHEADS + h], red[(w + 8) * NHEADS + h]);
        x = fmaxf(x, __shfl_xor(x, 8, 64));
        x = fmaxf(x, __shfl_xor(x, 16, 64));
        x = fmaxf(x, __shfl_xor(x, 32, 64));
        if (lane < NHEADS) gmax[lane] = x;
    }
    __syncthreads();
    float p[8];
    #pragma unroll
    for (int h = 0; h < NHEADS; ++h) {
        p[h] = __expf(v[h] - gmax[h]);
        pT[h * PT_STRIDE + t] = f2bf(p[h]);
    }
    #pragma unroll
    for (int h = 0; h < NHEADS; ++h) {
        float x = p[h];
        #pragma unroll
        for (int mask = 1; mask < 64; mask <<= 1)
            x += __shfl_xor(x, mask, 64);
        m8[h] = x;
    }
    if (lane == 0) {
        #pragma unroll
        for (int h = 0; h < NHEADS; ++h) red[wave * NHEADS + h] = m8[h];
    }
    __syncthreads();
    if (wave == 0) {
        int w = lane >> 3, h = lane & 7;
        float x = red[w * NHEADS + h] + red[(w + 8) * NHEADS + h];
        x += __shfl_xor(x, 8, 64);
        x += __shfl_xor(x, 16, 64);
        x += __shfl_xor(x, 32, 64);
        if (lane < NHEADS) gsum[lane] = x;
    }
    __syncthreads();

    // ---------------- phase 3: out[h][v] = (p @ values) / gsum via MFMA ----------------
    {
        const int n0 = wave * 16;                    // 16 waves x 16 cols = 256 v
        const float* vbase = values + (size_t)b * SLEN * VDIM + n0 + col;
        const unsigned short* arow = pT + col * PT_STRIDE + kgrp * 8;
        f32x4 acc = {0.f, 0.f, 0.f, 0.f};
        for (int kk = 0; kk < SLEN / 32; ++kk) {
            bf16x8 af = *(const bf16x8*)(arow + kk * 32);        // A[h=col][s], 16B ds_read
            int sb = kk * 32 + kgrp * 8;
            bf16x8 bf;
            unsigned short* bp = (unsigned short*)&bf;
            #pragma unroll
            for (int j = 0; j < 8; ++j)
                bp[j] = f2bf(vbase[(size_t)(sb + j) * VDIM]);    // B[s][v-col]
            acc = __builtin_amdgcn_mfma_f32_16x16x32_bf16(af, bf, acc, 0, 0, 0);
        }
        int rbase = kgrp * 4;
        if (rbase < NHEADS) {
            #pragma unroll
            for (int m = 0; m < 4; ++m) {
                int h = rbase + m;
                out[(size_t)b * NHEADS * VDIM + h * VDIM + n0 + col] = acc[m] / gsum[h];
            }
        }
    }
}

extern "C" void kernel_launch(void* const* d_in, const int* in_sizes, int n_in,
                              void* d_out, int out_size, void* d_ws, size_t ws_size,
                              hipStream_t stream) {
    const float* queries = (const float*)d_in[0];
    const float* keys    = (const float*)d_in[1];
    const float* values  = (const float*)d_in[2];
    const float* Wq      = (const float*)d_in[3];
    const float* bq      = (const float*)d_in[4];
    const float* Wk      = (const float*)d_in[5];
    const float* bk      = (const float*)d_in[6];
    float* out           = (float*)d_out;
    (void)in_sizes; (void)n_in; (void)out_size; (void)d_ws; (void)ws_size;

    attn_fused_kernel<<<dim3(256), dim3(1024), 0, stream>>>(
        queries, keys, values, Wq, bq, Wk, bk, out);
}